// Round 3
// baseline (415.696 us; speedup 1.0000x reference)
//
#include <hip/hip_runtime.h>
#include <hip/hip_bf16.h>

// QuadConv: out[N,64] = gather(features[N,32], neigh_idx[N,9] -> [N,288]) @ W.T + b
// N=500000, C_IN=32, C_OUT=64, K=9.  idx==-1 -> zero row.
//
// Round 2 (fixed compile): gather is the bottleneck (latency/L2-bound, 20% HBM, 3% MFMA).
//  - Pre-convert features to bf16 in d_ws (32 MB: fits aggregate L2) -> halves gather bytes
//  - Stage idx in LDS, fully unroll gather (9 loads in flight per thread)
//  - Nontemporal stores for out / loads for read-once streams (protect L2 for features)
//  - ext_vector_type for all nontemporal builtins (HIP float4/int4 are classes -> rejected)

typedef __bf16 bf16x8 __attribute__((ext_vector_type(8)));
typedef float  f32x16 __attribute__((ext_vector_type(16)));
typedef float  f32x4  __attribute__((ext_vector_type(4)));
typedef int    i32x4  __attribute__((ext_vector_type(4)));
typedef unsigned short ushort8 __attribute__((ext_vector_type(8)));

#define NPB   64      // nodes per block
#define PITCH 296     // bf16 elements per LDS row (288 + 8 pad) -> 592 B, 16B-aligned

__global__ __launch_bounds__(256) void cvt_bf16_kernel(
    const float* __restrict__ src, __bf16* __restrict__ dst, long long total)
{
    long long stride = (long long)gridDim.x * 256 * 8;
    for (long long i = ((long long)blockIdx.x * 256 + threadIdx.x) * 8;
         i + 7 < total; i += stride) {
        f32x4 f0 = __builtin_nontemporal_load((const f32x4*)(src + i));
        f32x4 f1 = __builtin_nontemporal_load((const f32x4*)(src + i + 4));
        bf16x8 v;
        v[0] = (__bf16)f0[0]; v[1] = (__bf16)f0[1]; v[2] = (__bf16)f0[2]; v[3] = (__bf16)f0[3];
        v[4] = (__bf16)f1[0]; v[5] = (__bf16)f1[1]; v[6] = (__bf16)f1[2]; v[7] = (__bf16)f1[3];
        *(bf16x8*)(dst + i) = v;   // hot data: keep cached in L2
    }
}

template<bool BF16F>
__global__ __launch_bounds__(256, 4) void quadconv_kernel(
    const float*  __restrict__ feat,   // [N,32] f32 (fallback path)
    const __bf16* __restrict__ fb,     // [N,32] bf16 in ws (fast path)
    const int*    __restrict__ nidx,   // [N,9]  i32, -1 = missing
    const float*  __restrict__ Wm,     // [64,288] f32
    const float*  __restrict__ bias,   // [64] f32
    float*        __restrict__ out,    // [N,64] f32
    int N)
{
    __shared__ __bf16 A[NPB][PITCH];   // 37888 B
    __shared__ int sIdx[NPB * 9];      //  2304 B   (total 40192 <= 40960 for 4 blocks/CU)

    const int tid  = threadIdx.x;
    const int lane = tid & 63;
    const int w    = tid >> 6;                    // wave 0..3
    const long long base = (long long)blockIdx.x * NPB;

    // ---------------- stage neighbor indices -> LDS ----------------
    if (base + NPB <= (long long)N) {
        if (tid < 144) {
            *(i32x4*)&sIdx[tid * 4] =
                __builtin_nontemporal_load((const i32x4*)&nidx[base * 9 + (long long)tid * 4]);
        }
    } else {
        for (int t = tid; t < NPB * 9; t += 256) {
            long long gi = base * 9 + t;
            sIdx[t] = (gi < (long long)N * 9) ? nidx[gi] : -1;
        }
    }

    // ---------------- W fragments -> registers (overlaps idx staging) ----------
    // Wave w: cols (w&1)*32 .. +31, nodes (w>>1)*32 .. +31.
    // B[k][n] = W[n][k]; lane holds B[k0+i][lane&31], k0 = kk*16 + (lane>>5)*8.
    const int colBase = (w & 1) * 32;
    const int col     = colBase + (lane & 31);
    const int khalf   = (lane >> 5) * 8;
    bf16x8 bw[18];
    #pragma unroll
    for (int kk = 0; kk < 18; ++kk) {
        const float* wp = Wm + col * 288 + kk * 16 + khalf;
        f32x4 w0 = *(const f32x4*)(wp);
        f32x4 w1 = *(const f32x4*)(wp + 4);
        bf16x8 v;
        v[0] = (__bf16)w0[0]; v[1] = (__bf16)w0[1]; v[2] = (__bf16)w0[2]; v[3] = (__bf16)w0[3];
        v[4] = (__bf16)w1[0]; v[5] = (__bf16)w1[1]; v[6] = (__bf16)w1[2]; v[7] = (__bf16)w1[3];
        bw[kk] = v;
    }
    const float bv = bias[col];

    __syncthreads();

    // ---------------- Phase 1: gather -> LDS (fully unrolled: 9 loads in flight) ----
    // 576 rows; 4 threads per row.
    const int q  = tid & 3;
    const int r0 = tid >> 2;
    #pragma unroll
    for (int it = 0; it < 9; ++it) {
        int r    = r0 + it * 64;                  // row id 0..575
        int node = r / 9;                         // local node 0..63
        int j    = r - node * 9;                  // neighbor 0..8
        int idx  = sIdx[r];
        if (BF16F) {
            ushort8 v = {0, 0, 0, 0, 0, 0, 0, 0};
            if (idx >= 0)
                v = *(const ushort8*)((const unsigned short*)fb + (long long)idx * 32 + q * 8);
            *(ushort8*)&A[node][j * 32 + q * 8] = v;
        } else {
            f32x4 f0 = {0.f, 0.f, 0.f, 0.f};
            f32x4 f1 = {0.f, 0.f, 0.f, 0.f};
            if (idx >= 0) {
                const float* sp = feat + (long long)idx * 32 + q * 8;
                f0 = *(const f32x4*)(sp);
                f1 = *(const f32x4*)(sp + 4);
            }
            bf16x8 v;
            v[0] = (__bf16)f0[0]; v[1] = (__bf16)f0[1]; v[2] = (__bf16)f0[2]; v[3] = (__bf16)f0[3];
            v[4] = (__bf16)f1[0]; v[5] = (__bf16)f1[1]; v[6] = (__bf16)f1[2]; v[7] = (__bf16)f1[3];
            *(bf16x8*)&A[node][j * 32 + q * 8] = v;
        }
    }

    __syncthreads();

    // ---------------- Phase 2: MFMA ----------------
    const int nodeOff = (w >> 1) * 32;
    const int arow    = nodeOff + (lane & 31);
    f32x16 acc;
    #pragma unroll
    for (int i = 0; i < 16; ++i) acc[i] = 0.0f;

    #pragma unroll
    for (int kk = 0; kk < 18; ++kk) {
        bf16x8 a = *(bf16x8*)&A[arow][kk * 16 + khalf];
        acc = __builtin_amdgcn_mfma_f32_32x32x16_bf16(a, bw[kk], acc, 0, 0, 0);
    }

    // ---------------- store (nontemporal: write-once stream) ----------------
    // D[m][n]: n = lane&31 (=col-colBase), m = (reg&3) + 4*(lane>>5) + 8*(reg>>2)
    const int hi = lane >> 5;
    #pragma unroll
    for (int reg = 0; reg < 16; ++reg) {
        int m = (reg & 3) + 4 * hi + 8 * (reg >> 2);
        long long node = base + nodeOff + m;
        if (node < (long long)N) {
            __builtin_nontemporal_store(acc[reg] + bv, &out[node * 64 + col]);
        }
    }
}

extern "C" void kernel_launch(void* const* d_in, const int* in_sizes, int n_in,
                              void* d_out, int out_size, void* d_ws, size_t ws_size,
                              hipStream_t stream) {
    const float* feat = (const float*)d_in[0];
    const int*   nidx = (const int*)d_in[1];
    const float* Wm   = (const float*)d_in[2];
    const float* bias = (const float*)d_in[3];
    float*       out  = (float*)d_out;

    int N = in_sizes[0] / 32;                 // features is [N,32]
    long long total = (long long)N * 32;
    int grid = (N + NPB - 1) / NPB;

    if (ws_size >= (size_t)(total * sizeof(__bf16))) {
        __bf16* fb = (__bf16*)d_ws;
        cvt_bf16_kernel<<<2048, 256, 0, stream>>>(feat, fb, total);
        quadconv_kernel<true><<<grid, 256, 0, stream>>>(feat, fb, nidx, Wm, bias, out, N);
    } else {
        quadconv_kernel<false><<<grid, 256, 0, stream>>>(feat, nullptr, nidx, Wm, bias, out, N);
    }
}

// Round 6
// 378.927 us; speedup vs baseline: 1.0970x; 1.0970x over previous
//
#include <hip/hip_runtime.h>
#include <hip/hip_bf16.h>

// QuadConv: out[N,64] = gather(features[N,32], neigh_idx[N,9] -> [N,288]) @ W.T + b
// N=500000, C_IN=32, C_OUT=64, K=9.  idx==-1 -> zero row.
//
// Round 4 kernel (2nd resubmit; r4/r5 benches were broker timeouts, no data):
//  latency x concurrency bound on gather (r3: dur flat at 255us, VALU 6.9%).
//  - REVERT nontemporal stores (r3: WRITE 125->461 MB, FETCH +164 MB = RMW damage)
//  - keep bf16 pre-converted features in d_ws (halves gather request bytes)
//  - overlap restructure: per-thread idx loads -> 9 gathers in flight -> ds_write
//    -> W-loads/cvt fill the gather-latency window -> ONE barrier -> MFMA.
//    (idx LDS staging + its barrier removed; W regs no longer coexist with gather regs)

typedef __bf16 bf16x8 __attribute__((ext_vector_type(8)));
typedef float  f32x16 __attribute__((ext_vector_type(16)));
typedef float  f32x4  __attribute__((ext_vector_type(4)));
typedef unsigned short ushort8 __attribute__((ext_vector_type(8)));

#define NPB   64      // nodes per block
#define PITCH 296     // bf16 elements per LDS row (288 + 8 pad) -> 592 B, 16B-aligned

__global__ __launch_bounds__(256) void cvt_bf16_kernel(
    const float* __restrict__ src, __bf16* __restrict__ dst, long long total)
{
    long long stride = (long long)gridDim.x * 256 * 8;
    for (long long i = ((long long)blockIdx.x * 256 + threadIdx.x) * 8;
         i + 7 < total; i += stride) {
        f32x4 f0 = __builtin_nontemporal_load((const f32x4*)(src + i));   // read-once stream
        f32x4 f1 = __builtin_nontemporal_load((const f32x4*)(src + i + 4));
        bf16x8 v;
        v[0] = (__bf16)f0[0]; v[1] = (__bf16)f0[1]; v[2] = (__bf16)f0[2]; v[3] = (__bf16)f0[3];
        v[4] = (__bf16)f1[0]; v[5] = (__bf16)f1[1]; v[6] = (__bf16)f1[2]; v[7] = (__bf16)f1[3];
        *(bf16x8*)(dst + i) = v;   // plain store: keep fb hot in L2/L3
    }
}

template<bool BF16F>
__global__ __launch_bounds__(256, 4) void quadconv_kernel(
    const float*  __restrict__ feat,   // [N,32] f32 (fallback path)
    const __bf16* __restrict__ fb,     // [N,32] bf16 in ws (fast path)
    const int*    __restrict__ nidx,   // [N,9]  i32, -1 = missing
    const float*  __restrict__ Wm,     // [64,288] f32
    const float*  __restrict__ bias,   // [64] f32
    float*        __restrict__ out,    // [N,64] f32
    int N)
{
    __shared__ __bf16 A[NPB][PITCH];   // 37888 B -> 4 blocks/CU

    const int tid  = threadIdx.x;
    const int lane = tid & 63;
    const int w    = tid >> 6;                    // wave 0..3
    const long long base = (long long)blockIdx.x * NPB;
    const long long idx_end = (long long)N * 9;

    // ---------------- phase A: neighbor indices, direct per-thread ----------------
    // thread handles rows r = (tid>>2) + 64*it; quads broadcast the same dword.
    const int q  = tid & 3;
    const int r0 = tid >> 2;
    int idxv[9];
    #pragma unroll
    for (int it = 0; it < 9; ++it) {
        long long gi = base * 9 + (r0 + it * 64);
        idxv[it] = (gi < idx_end) ? nidx[gi] : -1;
    }

    // ---------------- phase B: 9 gathers in flight -> LDS ----------------
    #pragma unroll
    for (int it = 0; it < 9; ++it) {
        int r    = r0 + it * 64;                  // row id 0..575
        int node = r / 9;                         // local node 0..63
        int j    = r - node * 9;                  // neighbor 0..8
        int idx  = idxv[it];
        if (BF16F) {
            ushort8 v = {0, 0, 0, 0, 0, 0, 0, 0};
            if (idx >= 0)
                v = *(const ushort8*)((const unsigned short*)fb + (long long)idx * 32 + q * 8);
            *(ushort8*)&A[node][j * 32 + q * 8] = v;
        } else {
            f32x4 f0 = {0.f, 0.f, 0.f, 0.f};
            f32x4 f1 = {0.f, 0.f, 0.f, 0.f};
            if (idx >= 0) {
                const float* sp = feat + (long long)idx * 32 + q * 8;
                f0 = *(const f32x4*)(sp);
                f1 = *(const f32x4*)(sp + 4);
            }
            bf16x8 v;
            v[0] = (__bf16)f0[0]; v[1] = (__bf16)f0[1]; v[2] = (__bf16)f0[2]; v[3] = (__bf16)f0[3];
            v[4] = (__bf16)f1[0]; v[5] = (__bf16)f1[1]; v[6] = (__bf16)f1[2]; v[7] = (__bf16)f1[3];
            *(bf16x8*)&A[node][j * 32 + q * 8] = v;
        }
    }

    // ---------------- phase C: W fragments -> registers (fills gather window) ------
    // Wave w: cols (w&1)*32 .. +31, nodes (w>>1)*32 .. +31.
    // B[k][n] = W[n][k]; lane holds B[k0+i][lane&31], k0 = kk*16 + (lane>>5)*8.
    const int colBase = (w & 1) * 32;
    const int col     = colBase + (lane & 31);
    const int khalf   = (lane >> 5) * 8;
    bf16x8 bw[18];
    #pragma unroll
    for (int kk = 0; kk < 18; ++kk) {
        const float* wp = Wm + col * 288 + kk * 16 + khalf;
        f32x4 w0 = *(const f32x4*)(wp);
        f32x4 w1 = *(const f32x4*)(wp + 4);
        bf16x8 v;
        v[0] = (__bf16)w0[0]; v[1] = (__bf16)w0[1]; v[2] = (__bf16)w0[2]; v[3] = (__bf16)w0[3];
        v[4] = (__bf16)w1[0]; v[5] = (__bf16)w1[1]; v[6] = (__bf16)w1[2]; v[7] = (__bf16)w1[3];
        bw[kk] = v;
    }
    const float bv = bias[col];

    __syncthreads();   // the ONLY barrier

    // ---------------- phase D: MFMA ----------------
    const int nodeOff = (w >> 1) * 32;
    const int arow    = nodeOff + (lane & 31);
    f32x16 acc;
    #pragma unroll
    for (int i = 0; i < 16; ++i) acc[i] = 0.0f;

    #pragma unroll
    for (int kk = 0; kk < 18; ++kk) {
        bf16x8 a = *(bf16x8*)&A[arow][kk * 16 + khalf];
        acc = __builtin_amdgcn_mfma_f32_32x32x16_bf16(a, bw[kk], acc, 0, 0, 0);
    }

    // ---------------- store (plain, coalesced 128B segments) ----------------
    // D[m][n]: n = lane&31 (=col-colBase), m = (reg&3) + 4*(lane>>5) + 8*(reg>>2)
    const int hi = lane >> 5;
    #pragma unroll
    for (int reg = 0; reg < 16; ++reg) {
        int m = (reg & 3) + 4 * hi + 8 * (reg >> 2);
        long long node = base + nodeOff + m;
        if (node < (long long)N) {
            out[node * 64 + col] = acc[reg] + bv;
        }
    }
}

extern "C" void kernel_launch(void* const* d_in, const int* in_sizes, int n_in,
                              void* d_out, int out_size, void* d_ws, size_t ws_size,
                              hipStream_t stream) {
    const float* feat = (const float*)d_in[0];
    const int*   nidx = (const int*)d_in[1];
    const float* Wm   = (const float*)d_in[2];
    const float* bias = (const float*)d_in[3];
    float*       out  = (float*)d_out;

    int N = in_sizes[0] / 32;                 // features is [N,32]
    long long total = (long long)N * 32;
    int grid = (N + NPB - 1) / NPB;

    if (ws_size >= (size_t)(total * sizeof(__bf16))) {
        __bf16* fb = (__bf16*)d_ws;
        cvt_bf16_kernel<<<2048, 256, 0, stream>>>(feat, fb, total);
        quadconv_kernel<true><<<grid, 256, 0, stream>>>(feat, fb, nidx, Wm, bias, out, N);
    } else {
        quadconv_kernel<false><<<grid, 256, 0, stream>>>(feat, nullptr, nidx, Wm, bias, out, N);
    }
}

// Round 7
// 309.499 us; speedup vs baseline: 1.3431x; 1.2243x over previous
//
#include <hip/hip_runtime.h>
#include <hip/hip_bf16.h>

// QuadConv: out[N,64] = gather(features[N,32], neigh_idx[N,9] -> [N,288]) @ W.T + b
// N=500000, C_IN=32, C_OUT=64, K=9.  idx==-1 -> zero row.
//
// Round 7: latency x concurrency bound (r6: 224us, VALU 8%, Mfma 3%, occ 43%).
//  - Gather DIRECTLY into MFMA A-fragments (no A-LDS tile, no per-tile barrier):
//    lane l's frag for K-step kk = 16 B at fb[idx[l&31][kk/2]*32 + (kk&1)*16 + (l>>5)*8]
//    (A-layout verified by the passing r1 kernel). Each 64B row still read exactly once.
//  - LDS holds only W: 36,864 B in (kk,half,lane)-contiguous layout -> conflict-free b128.
//  - 512-thread blocks (8 waves = 4 node-groups x 2 col-halves), __launch_bounds__(512,8)
//    -> VGPR cap 64 -> 4 blocks x 8 waves = 32 waves/CU (2x concurrency vs r6).
//  - 9 idx loads up-front; 3 gather-groups of 6 in flight (unroll-1 keeps pressure ~60).

typedef __bf16 bf16x8 __attribute__((ext_vector_type(8)));
typedef float  f32x16 __attribute__((ext_vector_type(16)));
typedef float  f32x4  __attribute__((ext_vector_type(4)));
typedef unsigned short ushort8 __attribute__((ext_vector_type(8)));

#define NPB 128   // nodes per block (8 waves: 4 node-groups of 32 x 2 col-halves)

__global__ __launch_bounds__(256) void cvt_bf16_kernel(
    const float* __restrict__ src, __bf16* __restrict__ dst, long long total)
{
    long long stride = (long long)gridDim.x * 256 * 8;
    for (long long i = ((long long)blockIdx.x * 256 + threadIdx.x) * 8;
         i + 7 < total; i += stride) {
        f32x4 f0 = __builtin_nontemporal_load((const f32x4*)(src + i));   // read-once stream
        f32x4 f1 = __builtin_nontemporal_load((const f32x4*)(src + i + 4));
        bf16x8 v;
        v[0] = (__bf16)f0[0]; v[1] = (__bf16)f0[1]; v[2] = (__bf16)f0[2]; v[3] = (__bf16)f0[3];
        v[4] = (__bf16)f1[0]; v[5] = (__bf16)f1[1]; v[6] = (__bf16)f1[2]; v[7] = (__bf16)f1[3];
        *(bf16x8*)(dst + i) = v;   // plain store: keep fb hot in L2/L3
    }
}

template<bool FAST>
__global__ __launch_bounds__(512, 8) void quadconv_kernel(
    const float*  __restrict__ feat,   // [N,32] f32 (fallback gather source)
    const __bf16* __restrict__ fb,     // [N,32] bf16 in ws (fast gather source)
    const int*    __restrict__ nidx,   // [N,9]  i32, -1 = missing
    const float*  __restrict__ Wm,     // [64,288] f32
    const float*  __restrict__ bias,   // [64] f32
    float*        __restrict__ out,    // [N,64] f32
    int N)
{
    // W fragments, conflict-free: entry c=(kk*2+half)*64+lane holds 8 bf16
    //   B[k=kk*16+(lane>>5)*8+i][col=half*32+(lane&31)] = W[col][k]
    __shared__ __bf16 Wl[2304 * 8];    // 36,864 B -> 4 blocks/CU

    const int tid  = threadIdx.x;
    const int lane = tid & 63;
    const int w    = tid >> 6;                    // wave 0..7

    // ---------------- fill W -> LDS (f32 read, L2-hot; cvt on the fly) ----------
    #pragma unroll
    for (int i = 0; i < 5; ++i) {
        int c = tid + i * 512;
        if (c < 2304) {
            int kk   = c >> 7;                    // /128
            int r    = c & 127;
            int half = r >> 6;
            int l    = r & 63;
            int row  = half * 32 + (l & 31);
            int col0 = kk * 16 + (l >> 5) * 8;
            const float* wp = Wm + row * 288 + col0;
            f32x4 w0 = *(const f32x4*)(wp);
            f32x4 w1 = *(const f32x4*)(wp + 4);
            bf16x8 v;
            v[0] = (__bf16)w0[0]; v[1] = (__bf16)w0[1]; v[2] = (__bf16)w0[2]; v[3] = (__bf16)w0[3];
            v[4] = (__bf16)w1[0]; v[5] = (__bf16)w1[1]; v[6] = (__bf16)w1[2]; v[7] = (__bf16)w1[3];
            *(bf16x8*)&Wl[c * 8] = v;
        }
    }

    const int half    = w & 1;                    // col half 0/1
    const int nodeOff = (w >> 1) * 32;            // 0/32/64/96
    const int klane   = (lane >> 5) * 8;          // channel sub-offset (0 or 8)
    const long long nbase = (long long)blockIdx.x * NPB + nodeOff;
    const long long row   = nbase + (lane & 31);
    const bool valid = row < (long long)N;

    const float bv = bias[half * 32 + (lane & 31)];

    // ---------------- 9 neighbor indices up-front (all in flight) ----------------
    int idxs[9];
    #pragma unroll
    for (int j = 0; j < 9; ++j)
        idxs[j] = valid ? nidx[row * 9 + j] : -1;

    __syncthreads();   // W ready; the only barrier

    f32x16 acc;
    #pragma unroll
    for (int i = 0; i < 16; ++i) acc[i] = 0.0f;

    bf16x8 zvec;
    #pragma unroll
    for (int i = 0; i < 8; ++i) zvec[i] = (__bf16)0.0f;

    // ---------------- main: 3 groups x (6 gathers in flight -> 6 MFMA) ----------
    #pragma unroll 1
    for (int g = 0; g < 3; ++g) {
        bf16x8 a[6];
        #pragma unroll
        for (int jj = 0; jj < 3; ++jj) {
            int id = idxs[g * 3 + jj];
            #pragma unroll
            for (int h = 0; h < 2; ++h) {
                bf16x8 v = zvec;
                if (id >= 0) {
                    if (FAST) {
                        v = *(const bf16x8*)(fb + (long long)id * 32 + h * 16 + klane);
                    } else {
                        const float* sp = feat + (long long)id * 32 + h * 16 + klane;
                        f32x4 f0 = *(const f32x4*)(sp);
                        f32x4 f1 = *(const f32x4*)(sp + 4);
                        v[0] = (__bf16)f0[0]; v[1] = (__bf16)f0[1]; v[2] = (__bf16)f0[2]; v[3] = (__bf16)f0[3];
                        v[4] = (__bf16)f1[0]; v[5] = (__bf16)f1[1]; v[6] = (__bf16)f1[2]; v[7] = (__bf16)f1[3];
                    }
                }
                a[jj * 2 + h] = v;
            }
        }
        #pragma unroll
        for (int jj = 0; jj < 3; ++jj) {
            #pragma unroll
            for (int h = 0; h < 2; ++h) {
                int kk = g * 6 + jj * 2 + h;
                bf16x8 b = *(const bf16x8*)&Wl[((kk * 2 + half) * 64 + lane) * 8];
                acc = __builtin_amdgcn_mfma_f32_32x32x16_bf16(a[jj * 2 + h], b, acc, 0, 0, 0);
            }
        }
    }

    // ---------------- store ----------------
    // D[m][n]: n = lane&31, m = (reg&3) + 4*(lane>>5) + 8*(reg>>2)
    const int hi  = lane >> 5;
    const int col = half * 32 + (lane & 31);
    #pragma unroll
    for (int reg = 0; reg < 16; ++reg) {
        int m = (reg & 3) + 4 * hi + 8 * (reg >> 2);
        long long node = nbase + m;
        if (node < (long long)N) {
            out[node * 64 + col] = acc[reg] + bv;
        }
    }
}

extern "C" void kernel_launch(void* const* d_in, const int* in_sizes, int n_in,
                              void* d_out, int out_size, void* d_ws, size_t ws_size,
                              hipStream_t stream) {
    const float* feat = (const float*)d_in[0];
    const int*   nidx = (const int*)d_in[1];
    const float* Wm   = (const float*)d_in[2];
    const float* bias = (const float*)d_in[3];
    float*       out  = (float*)d_out;

    int N = in_sizes[0] / 32;                 // features is [N,32]
    long long total = (long long)N * 32;
    int grid = (N + NPB - 1) / NPB;

    if (ws_size >= (size_t)(total * sizeof(__bf16))) {
        __bf16* fb = (__bf16*)d_ws;
        cvt_bf16_kernel<<<2048, 256, 0, stream>>>(feat, fb, total);
        quadconv_kernel<true><<<grid, 512, 0, stream>>>(feat, fb, nidx, Wm, bias, out, N);
    } else {
        quadconv_kernel<false><<<grid, 512, 0, stream>>>(feat, nullptr, nidx, Wm, bias, out, N);
    }
}

// Round 9
// 306.316 us; speedup vs baseline: 1.3571x; 1.0104x over previous
//
#include <hip/hip_runtime.h>
#include <hip/hip_bf16.h>

// QuadConv: out[N,64] = gather(features[N,32], neigh_idx[N,9] -> [N,288]) @ W.T + b
// N=500000, C_IN=32, C_OUT=64, K=9.  idx==-1 -> zero row.
//
// Round 8 (resubmit; r8 bench was a broker timeout, no data):
//  r7 hit 144us (occ 77%, 0 bank conflicts, 3.55 TB/s L2-miss path).
//  Still MLP-limited: ~150 outstanding reqs/CU vs ~220 needed (Little's law).
//  - Software-pipeline the gather: two 6-load groups in flight (12 reqs/wave):
//      load g0, load g1 -> mfma g0 || load g2 -> mfma g1 -> mfma g2
//  - __syncthreads BEFORE gather issues (drains only idx loads; gathers never
//    cross a barrier -> no vmcnt(0) drain of the deep pipeline)
//  - __launch_bounds__(512, 6): cap ~84 regs (incl 16 AGPR acc) -> 24 waves/CU
//    x 12 in flight ~= 288 outstanding (vs 150 in r7)
//  - nontemporal idx loads (read-once; preserve L2 for fb)

typedef __bf16 bf16x8 __attribute__((ext_vector_type(8)));
typedef float  f32x16 __attribute__((ext_vector_type(16)));
typedef float  f32x4  __attribute__((ext_vector_type(4)));

#define NPB 128   // nodes per block (8 waves: 4 node-groups of 32 x 2 col-halves)

__global__ __launch_bounds__(256) void cvt_bf16_kernel(
    const float* __restrict__ src, __bf16* __restrict__ dst, long long total)
{
    long long stride = (long long)gridDim.x * 256 * 8;
    for (long long i = ((long long)blockIdx.x * 256 + threadIdx.x) * 8;
         i + 7 < total; i += stride) {
        f32x4 f0 = __builtin_nontemporal_load((const f32x4*)(src + i));   // read-once stream
        f32x4 f1 = __builtin_nontemporal_load((const f32x4*)(src + i + 4));
        bf16x8 v;
        v[0] = (__bf16)f0[0]; v[1] = (__bf16)f0[1]; v[2] = (__bf16)f0[2]; v[3] = (__bf16)f0[3];
        v[4] = (__bf16)f1[0]; v[5] = (__bf16)f1[1]; v[6] = (__bf16)f1[2]; v[7] = (__bf16)f1[3];
        *(bf16x8*)(dst + i) = v;   // plain store: keep fb hot in L2/L3
    }
}

template<bool FAST>
__device__ __forceinline__ void load_group(
    bf16x8 (&A)[6], const int (&idxs)[9], int g,
    const __bf16* __restrict__ fb, const float* __restrict__ feat,
    int klane, bf16x8 zvec)
{
    #pragma unroll
    for (int jj = 0; jj < 3; ++jj) {
        int id = idxs[g * 3 + jj];
        #pragma unroll
        for (int h = 0; h < 2; ++h) {
            bf16x8 v = zvec;
            if (id >= 0) {
                if (FAST) {
                    v = *(const bf16x8*)(fb + (long long)id * 32 + h * 16 + klane);
                } else {
                    const float* sp = feat + (long long)id * 32 + h * 16 + klane;
                    f32x4 f0 = *(const f32x4*)(sp);
                    f32x4 f1 = *(const f32x4*)(sp + 4);
                    v[0] = (__bf16)f0[0]; v[1] = (__bf16)f0[1]; v[2] = (__bf16)f0[2]; v[3] = (__bf16)f0[3];
                    v[4] = (__bf16)f1[0]; v[5] = (__bf16)f1[1]; v[6] = (__bf16)f1[2]; v[7] = (__bf16)f1[3];
                }
            }
            A[jj * 2 + h] = v;
        }
    }
}

__device__ __forceinline__ void mfma_group(
    f32x16& acc, const bf16x8 (&A)[6], const __bf16* Wl, int g, int half, int lane)
{
    #pragma unroll
    for (int t = 0; t < 6; ++t) {
        int kk = g * 6 + t;
        bf16x8 b = *(const bf16x8*)&Wl[((kk * 2 + half) * 64 + lane) * 8];
        acc = __builtin_amdgcn_mfma_f32_32x32x16_bf16(A[t], b, acc, 0, 0, 0);
    }
}

template<bool FAST>
__global__ __launch_bounds__(512, 6) void quadconv_kernel(
    const float*  __restrict__ feat,   // [N,32] f32 (fallback gather source)
    const __bf16* __restrict__ fb,     // [N,32] bf16 in ws (fast gather source)
    const int*    __restrict__ nidx,   // [N,9]  i32, -1 = missing
    const float*  __restrict__ Wm,     // [64,288] f32
    const float*  __restrict__ bias,   // [64] f32
    float*        __restrict__ out,    // [N,64] f32
    int N)
{
    // W fragments, conflict-free: entry c=(kk*2+half)*64+lane holds 8 bf16
    //   B[k=kk*16+(lane>>5)*8+i][col=half*32+(lane&31)] = W[col][k]
    __shared__ __bf16 Wl[2304 * 8];    // 36,864 B

    const int tid  = threadIdx.x;
    const int lane = tid & 63;
    const int w    = tid >> 6;                    // wave 0..7

    // ---------------- fill W -> LDS (f32 read, L2-hot; cvt on the fly) ----------
    #pragma unroll
    for (int i = 0; i < 5; ++i) {
        int c = tid + i * 512;
        if (c < 2304) {
            int kk   = c >> 7;                    // /128
            int r    = c & 127;
            int half = r >> 6;
            int l    = r & 63;
            int row  = half * 32 + (l & 31);
            int col0 = kk * 16 + (l >> 5) * 8;
            const float* wp = Wm + row * 288 + col0;
            f32x4 w0 = *(const f32x4*)(wp);
            f32x4 w1 = *(const f32x4*)(wp + 4);
            bf16x8 v;
            v[0] = (__bf16)w0[0]; v[1] = (__bf16)w0[1]; v[2] = (__bf16)w0[2]; v[3] = (__bf16)w0[3];
            v[4] = (__bf16)w1[0]; v[5] = (__bf16)w1[1]; v[6] = (__bf16)w1[2]; v[7] = (__bf16)w1[3];
            *(bf16x8*)&Wl[c * 8] = v;
        }
    }

    const int half    = w & 1;                    // col half 0/1
    const int nodeOff = (w >> 1) * 32;            // 0/32/64/96
    const int klane   = (lane >> 5) * 8;          // channel sub-offset (0 or 8)
    const long long nbase = (long long)blockIdx.x * NPB + nodeOff;
    const long long row   = nbase + (lane & 31);
    const bool valid = row < (long long)N;

    const float bv = bias[half * 32 + (lane & 31)];

    // ---------------- 9 neighbor indices (nt: read-once stream) ----------------
    int idxs[9];
    #pragma unroll
    for (int j = 0; j < 9; ++j)
        idxs[j] = valid ? __builtin_nontemporal_load(nidx + row * 9 + j) : -1;

    __syncthreads();   // drains only idx loads + W ds_writes; gathers issue after

    f32x16 acc;
    #pragma unroll
    for (int i = 0; i < 16; ++i) acc[i] = 0.0f;

    bf16x8 zvec;
    #pragma unroll
    for (int i = 0; i < 8; ++i) zvec[i] = (__bf16)0.0f;

    // ---------------- pipelined gather/MFMA: 12 loads in flight ----------------
    bf16x8 a0[6], a1[6];
    load_group<FAST>(a0, idxs, 0, fb, feat, klane, zvec);
    load_group<FAST>(a1, idxs, 1, fb, feat, klane, zvec);
    mfma_group(acc, a0, Wl, 0, half, lane);       // waits a0; a1 + (next) in flight
    load_group<FAST>(a0, idxs, 2, fb, feat, klane, zvec);
    mfma_group(acc, a1, Wl, 1, half, lane);
    mfma_group(acc, a0, Wl, 2, half, lane);

    // ---------------- store ----------------
    // D[m][n]: n = lane&31, m = (reg&3) + 4*(lane>>5) + 8*(reg>>2)
    const int hi  = lane >> 5;
    const int col = half * 32 + (lane & 31);
    #pragma unroll
    for (int reg = 0; reg < 16; ++reg) {
        int m = (reg & 3) + 4 * hi + 8 * (reg >> 2);
        long long node = nbase + m;
        if (node < (long long)N) {
            out[node * 64 + col] = acc[reg] + bv;
        }
    }
}

extern "C" void kernel_launch(void* const* d_in, const int* in_sizes, int n_in,
                              void* d_out, int out_size, void* d_ws, size_t ws_size,
                              hipStream_t stream) {
    const float* feat = (const float*)d_in[0];
    const int*   nidx = (const int*)d_in[1];
    const float* Wm   = (const float*)d_in[2];
    const float* bias = (const float*)d_in[3];
    float*       out  = (float*)d_out;

    int N = in_sizes[0] / 32;                 // features is [N,32]
    long long total = (long long)N * 32;
    int grid = (N + NPB - 1) / NPB;

    if (ws_size >= (size_t)(total * sizeof(__bf16))) {
        __bf16* fb = (__bf16*)d_ws;
        cvt_bf16_kernel<<<2048, 256, 0, stream>>>(feat, fb, total);
        quadconv_kernel<true><<<grid, 512, 0, stream>>>(feat, fb, nidx, Wm, bias, out, N);
    } else {
        quadconv_kernel<false><<<grid, 512, 0, stream>>>(feat, nullptr, nidx, Wm, bias, out, N);
    }
}

// Round 10
// 295.135 us; speedup vs baseline: 1.4085x; 1.0379x over previous
//
#include <hip/hip_runtime.h>
#include <hip/hip_bf16.h>

// QuadConv: out[N,64] = gather(features[N,32], neigh_idx[N,9] -> [N,288]) @ W.T + b
// N=500000, C_IN=32, C_OUT=64, K=9.  idx==-1 -> zero row.
//
// Round 10: r7 (25w x 6 in-flight) and r9 (19w x 12) both pin at 142-144us,
//  FETCH ~= unique gather footprint (288 MB) at ~2.05 TB/s -> wall is downstream
//  (L3 sector throughput OR request-queue occupancy). Experiment: halve request
//  count per row. fb stored PERMUTED per 32-elem row: [c00|c10|c01|c11] where
//  c(kk,hi) = channels [kk*16+hi*8, +8). Lane l then loads BOTH its K-step frags
//  as ONE 32 B dwordx4 at row*64B + (l>>5)*32B; lanes l,l+32 merge -> one 64 B
//  request per row (was 2 instrs / 2 requests). Gather instrs 18 -> 9 per wave.
//  Flat result => L3 scattered-sector wall => roofline.

typedef __bf16 bf16x8  __attribute__((ext_vector_type(8)));
typedef __bf16 bf16x16 __attribute__((ext_vector_type(16)));
typedef float  f32x16  __attribute__((ext_vector_type(16)));
typedef float  f32x4   __attribute__((ext_vector_type(4)));

#define NPB 128   // nodes per block (8 waves: 4 node-groups of 32 x 2 col-halves)

// cvt + per-row chunk permute: thread q in [0,4) of each row reads elems [q*8,+8)
// and writes them to chunk position perm(q) = {0->0, 1->2, 2->1, 3->3} (bit swap).
__global__ __launch_bounds__(256) void cvt_bf16_kernel(
    const float* __restrict__ src, __bf16* __restrict__ dst, long long total)
{
    long long stride = (long long)gridDim.x * 256 * 8;
    for (long long i = ((long long)blockIdx.x * 256 + threadIdx.x) * 8;
         i + 7 < total; i += stride) {
        f32x4 f0 = __builtin_nontemporal_load((const f32x4*)(src + i));   // read-once stream
        f32x4 f1 = __builtin_nontemporal_load((const f32x4*)(src + i + 4));
        bf16x8 v;
        v[0] = (__bf16)f0[0]; v[1] = (__bf16)f0[1]; v[2] = (__bf16)f0[2]; v[3] = (__bf16)f0[3];
        v[4] = (__bf16)f1[0]; v[5] = (__bf16)f1[1]; v[6] = (__bf16)f1[2]; v[7] = (__bf16)f1[3];
        long long row = i >> 5;
        int q = (int)((i >> 3) & 3);
        int p = ((q << 1) | (q >> 1)) & 3;        // 0,2,1,3
        *(bf16x8*)(dst + row * 32 + p * 8) = v;
    }
}

template<bool FAST>
__device__ __forceinline__ void load_rows(
    bf16x16 (&A)[3], const int (&idxs)[9], int g,
    const __bf16* __restrict__ fb, const float* __restrict__ feat,
    int hi, bf16x16 zvec)
{
    #pragma unroll
    for (int jj = 0; jj < 3; ++jj) {
        int id = idxs[g * 3 + jj];
        bf16x16 v = zvec;
        if (id >= 0) {
            if (FAST) {
                // permuted row: one 32 B load = frags for kk=2j (lo) and kk=2j+1 (hi)
                v = *(const bf16x16*)(fb + (long long)id * 32 + hi * 16);
            } else {
                const float* sp = feat + (long long)id * 32;
                f32x4 f0 = *(const f32x4*)(sp + hi * 8);
                f32x4 f1 = *(const f32x4*)(sp + hi * 8 + 4);
                f32x4 f2 = *(const f32x4*)(sp + 16 + hi * 8);
                f32x4 f3 = *(const f32x4*)(sp + 16 + hi * 8 + 4);
                v[0]  = (__bf16)f0[0]; v[1]  = (__bf16)f0[1]; v[2]  = (__bf16)f0[2]; v[3]  = (__bf16)f0[3];
                v[4]  = (__bf16)f1[0]; v[5]  = (__bf16)f1[1]; v[6]  = (__bf16)f1[2]; v[7]  = (__bf16)f1[3];
                v[8]  = (__bf16)f2[0]; v[9]  = (__bf16)f2[1]; v[10] = (__bf16)f2[2]; v[11] = (__bf16)f2[3];
                v[12] = (__bf16)f3[0]; v[13] = (__bf16)f3[1]; v[14] = (__bf16)f3[2]; v[15] = (__bf16)f3[3];
            }
        }
        A[jj] = v;
    }
}

__device__ __forceinline__ void mfma_rows(
    f32x16& acc, const bf16x16 (&A)[3], const __bf16* Wl, int g, int half, int lane)
{
    #pragma unroll
    for (int jj = 0; jj < 3; ++jj) {
        int kk = (g * 3 + jj) * 2;
        bf16x8 lo = __builtin_shufflevector(A[jj], A[jj], 0, 1, 2, 3, 4, 5, 6, 7);
        bf16x8 hi = __builtin_shufflevector(A[jj], A[jj], 8, 9, 10, 11, 12, 13, 14, 15);
        bf16x8 b0 = *(const bf16x8*)&Wl[((kk * 2 + half) * 64 + lane) * 8];
        acc = __builtin_amdgcn_mfma_f32_32x32x16_bf16(lo, b0, acc, 0, 0, 0);
        bf16x8 b1 = *(const bf16x8*)&Wl[(((kk + 1) * 2 + half) * 64 + lane) * 8];
        acc = __builtin_amdgcn_mfma_f32_32x32x16_bf16(hi, b1, acc, 0, 0, 0);
    }
}

template<bool FAST>
__global__ __launch_bounds__(512, 4) void quadconv_kernel(
    const float*  __restrict__ feat,   // [N,32] f32 (fallback gather source)
    const __bf16* __restrict__ fb,     // [N,32] bf16 PERMUTED in ws (fast source)
    const int*    __restrict__ nidx,   // [N,9]  i32, -1 = missing
    const float*  __restrict__ Wm,     // [64,288] f32
    const float*  __restrict__ bias,   // [64] f32
    float*        __restrict__ out,    // [N,64] f32
    int N)
{
    // W fragments, conflict-free: entry c=(kk*2+half)*64+lane holds 8 bf16
    //   B[k=kk*16+(lane>>5)*8+i][col=half*32+(lane&31)] = W[col][k]
    __shared__ __bf16 Wl[2304 * 8];    // 36,864 B

    const int tid  = threadIdx.x;
    const int lane = tid & 63;
    const int w    = tid >> 6;                    // wave 0..7

    // ---------------- fill W -> LDS (f32 read, L2-hot; cvt on the fly) ----------
    #pragma unroll
    for (int i = 0; i < 5; ++i) {
        int c = tid + i * 512;
        if (c < 2304) {
            int kk   = c >> 7;                    // /128
            int r    = c & 127;
            int half = r >> 6;
            int l    = r & 63;
            int row  = half * 32 + (l & 31);
            int col0 = kk * 16 + (l >> 5) * 8;
            const float* wp = Wm + row * 288 + col0;
            f32x4 w0 = *(const f32x4*)(wp);
            f32x4 w1 = *(const f32x4*)(wp + 4);
            bf16x8 v;
            v[0] = (__bf16)w0[0]; v[1] = (__bf16)w0[1]; v[2] = (__bf16)w0[2]; v[3] = (__bf16)w0[3];
            v[4] = (__bf16)w1[0]; v[5] = (__bf16)w1[1]; v[6] = (__bf16)w1[2]; v[7] = (__bf16)w1[3];
            *(bf16x8*)&Wl[c * 8] = v;
        }
    }

    const int half    = w & 1;                    // col half 0/1
    const int nodeOff = (w >> 1) * 32;            // 0/32/64/96
    const int hi      = lane >> 5;                // which 32 B half of the row
    const long long nbase = (long long)blockIdx.x * NPB + nodeOff;
    const long long row   = nbase + (lane & 31);
    const bool valid = row < (long long)N;

    const float bv = bias[half * 32 + (lane & 31)];

    // ---------------- 9 neighbor indices (nt: read-once stream) ----------------
    int idxs[9];
    #pragma unroll
    for (int j = 0; j < 9; ++j)
        idxs[j] = valid ? __builtin_nontemporal_load(nidx + row * 9 + j) : -1;

    __syncthreads();   // drains only idx loads + W ds_writes; gathers issue after

    f32x16 acc;
    #pragma unroll
    for (int i = 0; i < 16; ++i) acc[i] = 0.0f;

    bf16x16 zvec;
    #pragma unroll
    for (int i = 0; i < 16; ++i) zvec[i] = (__bf16)0.0f;

    // ---------------- pipelined gather/MFMA: 6 row-loads (64 B reqs) in flight ----
    bf16x16 a0[3], a1[3];
    load_rows<FAST>(a0, idxs, 0, fb, feat, hi, zvec);
    load_rows<FAST>(a1, idxs, 1, fb, feat, hi, zvec);
    mfma_rows(acc, a0, Wl, 0, half, lane);        // waits a0; a1 + next in flight
    load_rows<FAST>(a0, idxs, 2, fb, feat, hi, zvec);
    mfma_rows(acc, a1, Wl, 1, half, lane);
    mfma_rows(acc, a0, Wl, 2, half, lane);

    // ---------------- store ----------------
    // D[m][n]: n = lane&31, m = (reg&3) + 4*(lane>>5) + 8*(reg>>2)
    const int col = half * 32 + (lane & 31);
    #pragma unroll
    for (int reg = 0; reg < 16; ++reg) {
        int m = (reg & 3) + 4 * hi + 8 * (reg >> 2);
        long long node = nbase + m;
        if (node < (long long)N) {
            out[node * 64 + col] = acc[reg] + bv;
        }
    }
}

extern "C" void kernel_launch(void* const* d_in, const int* in_sizes, int n_in,
                              void* d_out, int out_size, void* d_ws, size_t ws_size,
                              hipStream_t stream) {
    const float* feat = (const float*)d_in[0];
    const int*   nidx = (const int*)d_in[1];
    const float* Wm   = (const float*)d_in[2];
    const float* bias = (const float*)d_in[3];
    float*       out  = (float*)d_out;

    int N = in_sizes[0] / 32;                 // features is [N,32]
    long long total = (long long)N * 32;
    int grid = (N + NPB - 1) / NPB;

    if (ws_size >= (size_t)(total * sizeof(__bf16))) {
        __bf16* fb = (__bf16*)d_ws;
        cvt_bf16_kernel<<<2048, 256, 0, stream>>>(feat, fb, total);
        quadconv_kernel<true><<<grid, 512, 0, stream>>>(feat, fb, nidx, Wm, bias, out, N);
    } else {
        quadconv_kernel<false><<<grid, 512, 0, stream>>>(feat, nullptr, nidx, Wm, bias, out, N);
    }
}

// Round 13
// 286.408 us; speedup vs baseline: 1.4514x; 1.0305x over previous
//
#include <hip/hip_runtime.h>
#include <hip/hip_bf16.h>

// QuadConv: out[N,64] = gather(features[N,32], neigh_idx[N,9] -> [N,288]) @ W.T + b
// N=500000, C_IN=32, C_OUT=64, K=9.  idx==-1 -> zero row.
//
// Round 11 kernel (3rd submit; r11/r12 benches were broker timeouts, no data):
//  r10 showed 2 instrs (32B/lane) per row => still 4 line-requests per
//  row-read event (2 per wave x 2 col-half waves), ~18M total, ~137 G req/s ->
//  suspected TA/TCP request-rate wall (bytes already minimal: FETCH ~= 1 line/event).
//  Switch to mfma_f32_16x16x32_bf16: its A-layout (row=lane&15, k=(lane>>4)*8+i)
//  makes the 4 lanes of a row request its 4 contiguous 16B chunks IN ONE
//  INSTRUCTION -> exactly 1 coalesced 64B line-request per row, no shuffles.
//  K=32 = one neighbor row per MFMA step. Each wave: 16 nodes x ALL 64 cols
//  (A-frag reused across 4 B-tiles from LDS) -> 1 request per row-read event
//  (was 4). Total gather requests 18M -> 4.5M.  fb back to natural layout.
//  Pre-committed: 70-105us => request-rate wall confirmed; flat ~130 => L3
//  byte-service wall => roofline.

typedef __bf16 bf16x8 __attribute__((ext_vector_type(8)));
typedef float  f32x4  __attribute__((ext_vector_type(4)));

#define NPB 128   // nodes per block = 8 waves x 16 nodes

__global__ __launch_bounds__(256) void cvt_bf16_kernel(
    const float* __restrict__ src, __bf16* __restrict__ dst, long long total)
{
    long long stride = (long long)gridDim.x * 256 * 8;
    for (long long i = ((long long)blockIdx.x * 256 + threadIdx.x) * 8;
         i + 7 < total; i += stride) {
        f32x4 f0 = __builtin_nontemporal_load((const f32x4*)(src + i));   // read-once stream
        f32x4 f1 = __builtin_nontemporal_load((const f32x4*)(src + i + 4));
        bf16x8 v;
        v[0] = (__bf16)f0[0]; v[1] = (__bf16)f0[1]; v[2] = (__bf16)f0[2]; v[3] = (__bf16)f0[3];
        v[4] = (__bf16)f1[0]; v[5] = (__bf16)f1[1]; v[6] = (__bf16)f1[2]; v[7] = (__bf16)f1[3];
        *(bf16x8*)(dst + i) = v;   // plain store: keep fb hot in L2/L3
    }
}

template<bool FAST>
__global__ __launch_bounds__(512, 4) void quadconv_kernel(
    const float*  __restrict__ feat,   // [N,32] f32 (fallback gather source)
    const __bf16* __restrict__ fb,     // [N,32] bf16 natural layout (fast source)
    const int*    __restrict__ nidx,   // [N,9]  i32, -1 = missing
    const float*  __restrict__ Wm,     // [64,288] f32
    const float*  __restrict__ bias,   // [64] f32
    float*        __restrict__ out,    // [N,64] f32
    int N)
{
    // W fragments for 16x16x32: entry c=(j*4+t)*64+lane holds 8 bf16:
    //   B[k = j*32 + (lane>>4)*8 + i][col = t*16 + (lane&15)] = W[col][k]
    // per-lane 16B ds_read_b128, contiguous across lanes -> conflict-free.
    __shared__ __bf16 Wl[2304 * 8];    // 36,864 B

    const int tid  = threadIdx.x;
    const int lane = tid & 63;
    const int w    = tid >> 6;                    // wave 0..7
    const int c4   = lane >> 4;                   // chunk / row-subgroup 0..3
    const int n16  = lane & 15;                   // node-in-wave / col-in-tile

    // ---------------- fill W -> LDS (f32 read, L2-hot; cvt on the fly) ----------
    #pragma unroll
    for (int i = 0; i < 5; ++i) {
        int c = tid + i * 512;
        if (c < 2304) {
            int j = c >> 8;                       // neighbor 0..8
            int t = (c >> 6) & 3;                 // col tile 0..3
            int l = c & 63;
            int col = t * 16 + (l & 15);
            int k0  = j * 32 + (l >> 4) * 8;
            const float* wp = Wm + col * 288 + k0;
            f32x4 w0 = *(const f32x4*)(wp);
            f32x4 w1 = *(const f32x4*)(wp + 4);
            bf16x8 v;
            v[0] = (__bf16)w0[0]; v[1] = (__bf16)w0[1]; v[2] = (__bf16)w0[2]; v[3] = (__bf16)w0[3];
            v[4] = (__bf16)w1[0]; v[5] = (__bf16)w1[1]; v[6] = (__bf16)w1[2]; v[7] = (__bf16)w1[3];
            *(bf16x8*)&Wl[c * 8] = v;
        }
    }

    const long long nb   = (long long)blockIdx.x * NPB + w * 16;   // wave's 16 nodes
    const long long node = nb + n16;
    const bool valid = node < (long long)N;

    // bias values for the 4 col tiles (tiny, L2-hot)
    float bv[4];
    #pragma unroll
    for (int t = 0; t < 4; ++t) bv[t] = bias[t * 16 + n16];

    // ---------------- 9 neighbor indices (nt: read-once stream) ----------------
    int idxs[9];
    #pragma unroll
    for (int j = 0; j < 9; ++j)
        idxs[j] = valid ? __builtin_nontemporal_load(nidx + node * 9 + j) : -1;

    __syncthreads();   // W ready; gathers issue after (never drained by a barrier)

    bf16x8 zvec;
    #pragma unroll
    for (int i = 0; i < 8; ++i) zvec[i] = (__bf16)0.0f;

    // ---------------- gather: 9 instrs, 1 coalesced 64B line-request per row ----
    // lane l loads row idxs[j] (node n16), bytes [c4*16, +16): the 4 c4-lanes
    // cover the full 64B row in ONE instruction.
    bf16x8 a[9];
    #pragma unroll
    for (int j = 0; j < 9; ++j) {
        bf16x8 v = zvec;
        int id = idxs[j];
        if (id >= 0) {
            if (FAST) {
                v = *(const bf16x8*)(fb + (long long)id * 32 + c4 * 8);
            } else {
                const float* sp = feat + (long long)id * 32 + c4 * 8;
                f32x4 f0 = *(const f32x4*)(sp);
                f32x4 f1 = *(const f32x4*)(sp + 4);
                v[0] = (__bf16)f0[0]; v[1] = (__bf16)f0[1]; v[2] = (__bf16)f0[2]; v[3] = (__bf16)f0[3];
                v[4] = (__bf16)f1[0]; v[5] = (__bf16)f1[1]; v[6] = (__bf16)f1[2]; v[7] = (__bf16)f1[3];
            }
        }
        a[j] = v;
    }

    // ---------------- MFMA: 9 K-steps x 4 col tiles, A-frag reused 4x ----------
    f32x4 acc[4];
    #pragma unroll
    for (int t = 0; t < 4; ++t) { acc[t][0] = 0.f; acc[t][1] = 0.f; acc[t][2] = 0.f; acc[t][3] = 0.f; }

    #pragma unroll
    for (int j = 0; j < 9; ++j) {
        #pragma unroll
        for (int t = 0; t < 4; ++t) {
            bf16x8 b = *(const bf16x8*)&Wl[((j * 4 + t) * 64 + lane) * 8];
            acc[t] = __builtin_amdgcn_mfma_f32_16x16x32_bf16(a[j], b, acc[t], 0, 0, 0);
        }
    }

    // ---------------- store ----------------
    // D[m][n] (16x16): n = lane&15, m = (lane>>4)*4 + reg
    #pragma unroll
    for (int reg = 0; reg < 4; ++reg) {
        long long nd = nb + c4 * 4 + reg;
        if (nd < (long long)N) {
            #pragma unroll
            for (int t = 0; t < 4; ++t) {
                out[nd * 64 + t * 16 + n16] = acc[t][reg] + bv[t];
            }
        }
    }
}

extern "C" void kernel_launch(void* const* d_in, const int* in_sizes, int n_in,
                              void* d_out, int out_size, void* d_ws, size_t ws_size,
                              hipStream_t stream) {
    const float* feat = (const float*)d_in[0];
    const int*   nidx = (const int*)d_in[1];
    const float* Wm   = (const float*)d_in[2];
    const float* bias = (const float*)d_in[3];
    float*       out  = (float*)d_out;

    int N = in_sizes[0] / 32;                 // features is [N,32]
    long long total = (long long)N * 32;
    int grid = (N + NPB - 1) / NPB;

    if (ws_size >= (size_t)(total * sizeof(__bf16))) {
        __bf16* fb = (__bf16*)d_ws;
        cvt_bf16_kernel<<<2048, 256, 0, stream>>>(feat, fb, total);
        quadconv_kernel<true><<<grid, 512, 0, stream>>>(feat, fb, nidx, Wm, bias, out, N);
    } else {
        quadconv_kernel<false><<<grid, 512, 0, stream>>>(feat, nullptr, nidx, Wm, bias, out, N);
    }
}